// Round 5
// baseline (148.088 us; speedup 1.0000x reference)
//
#include <hip/hip_runtime.h>
#include <math.h>

#define NN 8192
#define CC 256
#define LOG2N 13

typedef float f32x4 __attribute__((ext_vector_type(4)));

// ---------------- ws layout (floats) ----------------
// aggP : [128][256]  floats [0, 32768)
// zrP  : [28][256]   floats [32768, 39936)   m*4+q; m:0=Wxz 1=Whz 2=Cz 3=Wxr 4=Whr 5=Cr 6=Wxh
// cnt  : 2 uints at float offset 39936
#define WS_AGGP 0
#define WS_ZRP  32768
#define WS_CNT  39936

#define NAGG    128
#define NMV     28
#define BID_EPI (NAGG + NMV)   // 156
#define STREAM0 (BID_EPI + 1)  // 157
#define NSTREAM 2048

__global__ void __launch_bounds__(256) k_fused(
        const float* __restrict__ X, const float* __restrict__ E,
        const float* __restrict__ H,
        const int* __restrict__ dh, const int* __restrict__ dt,
        const float* __restrict__ Wxz, const float* __restrict__ Whz,
        const float* __restrict__ Cz,  const float* __restrict__ Wxr,
        const float* __restrict__ Whr, const float* __restrict__ Cr,
        const float* __restrict__ Wxh, const float* __restrict__ Whh,
        const float* __restrict__ bz, const float* __restrict__ br,
        const float* __restrict__ bh,
        float* __restrict__ ws, unsigned* __restrict__ cnt,
        float* __restrict__ out) {
    const int bid = blockIdx.x;
    const int t = threadIdx.x;
    const int head = dh[0], tail = dt[0];
    const size_t nn = (size_t)NN * NN;
    float* aggP = ws + WS_AGGP;
    float* zrP  = ws + WS_ZRP;

    if (bid >= STREAM0) {
        // ---- pure E streaming: E_new = 0.5*E (+ head-row special case) ----
        const int s = bid - STREAM0;
        const size_t base = (size_t)s * 8192 + t;  // in f32x4 units
        #pragma unroll 4
        for (int k = 0; k < 32; ++k) {
            const size_t idx = base + (size_t)k * 256;
            const size_t e = idx << 2;
            const f32x4 v = __builtin_nontemporal_load((const f32x4*)(E + e));
            f32x4 o = v * 0.5f;
            const int i = (int)(e >> LOG2N);
            if (i == head) {
                const int j = (int)(e & (NN - 1));
                if (head != tail) {
                    const f32x4 w = *(const f32x4*)(E + (size_t)tail * NN + j);
                    o += w * 0.5f;
                }
                if (tail >= j && tail < j + 4) o[tail - j] += 0.5f;
            }
            *(f32x4*)(out + e) = o;
        }
        return;
    }

    if (bid < NAGG) {
        // ---- agg partials for rows [bid*64, bid*64+64) + H->out copy (single H read) ----
        __shared__ float e_sh[64];
        __shared__ f32x4 red[4][64];
        const int i0 = bid * 64;
        if (t < 64) {
            const int i = i0 + t;
            float e = 0.5f * E[(size_t)head * NN + i];
            if (head != tail) e += 0.5f * E[(size_t)tail * NN + i];
            if (i == tail) e += 0.5f;
            e_sh[t] = e;
        }
        __syncthreads();
        const int g = t >> 6, c = (t & 63) << 2;
        f32x4 acc = {0.f, 0.f, 0.f, 0.f};
        #pragma unroll
        for (int it = 0; it < 16; ++it) {
            const int r = it * 4 + g;
            const int row = i0 + r;
            const f32x4 hv = __builtin_nontemporal_load(
                (const f32x4*)(H + (size_t)row * CC + c));
            acc += hv * e_sh[r];
            if (row != head)
                *(f32x4*)(out + nn + (size_t)row * CC + c) = hv;
        }
        red[g][t & 63] = acc;
        __syncthreads();
        if (g == 0) {
            const f32x4 sv = red[0][t] + red[1][t] + red[2][t] + red[3][t];
            *(f32x4*)(aggP + bid * CC + (t << 2)) = sv;
        }
        __threadfence();
        __syncthreads();
        if (t == 0)
            __hip_atomic_fetch_add(&cnt[0], 1u, __ATOMIC_RELEASE, __HIP_MEMORY_SCOPE_AGENT);
        return;
    }

    if (bid < BID_EPI) {
        // ---- 7 matvec partial sets; only agg-consumers (m=2,5) wait on flag0 ----
        const int mb = bid - NAGG;
        const int m = mb >> 2, q = mb & 3;
        __shared__ float v_sh[64];
        const float* W;
        switch (m) {
            case 0: W = Wxz; break; case 1: W = Whz; break; case 2: W = Cz; break;
            case 3: W = Wxr; break; case 4: W = Whr; break; case 5: W = Cr; break;
            default: W = Wxh; break;
        }
        if (m == 2 || m == 5) {
            if (t == 0) {
                while (__hip_atomic_load(&cnt[0], __ATOMIC_ACQUIRE,
                                         __HIP_MEMORY_SCOPE_AGENT) < NAGG)
                    __builtin_amdgcn_s_sleep(1);
            }
            __syncthreads();
        }
        if (t < 64) {
            const int k = q * 64 + t;
            float v;
            if (m == 1 || m == 4)      v = H[(size_t)head * CC + k];
            else if (m == 2 || m == 5) { v = 0.f; for (int b = 0; b < NAGG; ++b) v += aggP[b * CC + k]; }
            else                       v = X[k];
            v_sh[t] = v;
        }
        __syncthreads();
        float acc = 0.f;
        #pragma unroll
        for (int kk = 0; kk < 64; ++kk)
            acc += v_sh[kk] * W[(size_t)(q * 64 + kk) * CC + t];
        zrP[mb * CC + t] = acc;
        __threadfence();
        __syncthreads();
        if (t == 0)
            __hip_atomic_fetch_add(&cnt[1], 1u, __ATOMIC_RELEASE, __HIP_MEMORY_SCOPE_AGENT);
        return;
    }

    // ---- bid == BID_EPI: GRU epilogue + head row of H_new ----
    {
        if (t == 0) {
            while (__hip_atomic_load(&cnt[1], __ATOMIC_ACQUIRE,
                                     __HIP_MEMORY_SCOPE_AGENT) < NMV)
                __builtin_amdgcn_s_sleep(1);
        }
        __syncthreads();
        __shared__ float rs_sh[CC];
        const int c = t;
        float sz = bz[c], sr = br[c];
        #pragma unroll
        for (int p = 0; p < 12; ++p)  sz += zrP[p * CC + c];
        #pragma unroll
        for (int p = 12; p < 24; ++p) sr += zrP[p * CC + c];
        const float z = 1.f / (1.f + expf(-sz));
        const float r = 1.f / (1.f + expf(-sr));
        const float h = H[(size_t)head * CC + c];
        rs_sh[c] = h * r;
        __syncthreads();
        float acc = 0.f;
        #pragma unroll 16
        for (int k = 0; k < CC; ++k)
            acc += rs_sh[k] * Whh[(size_t)k * CC + c];
        float s = bh[c] + acc;
        #pragma unroll
        for (int p = 24; p < 28; ++p) s += zrP[p * CC + c];
        const float ht = tanhf(s);
        out[nn + (size_t)head * CC + c] = z * h + (1.f - z) * ht;
    }
}

extern "C" void kernel_launch(void* const* d_in, const int* in_sizes, int n_in,
                              void* d_out, int out_size, void* d_ws, size_t ws_size,
                              hipStream_t stream) {
    const float* X    = (const float*)d_in[0];
    const int*   dh   = (const int*)d_in[1];
    const int*   dt   = (const int*)d_in[2];
    const float* E    = (const float*)d_in[3];
    const float* H    = (const float*)d_in[4];
    const float* Wxz  = (const float*)d_in[5];
    const float* Whz  = (const float*)d_in[6];
    const float* Cz   = (const float*)d_in[7];
    const float* bz   = (const float*)d_in[8];
    const float* Wxr  = (const float*)d_in[9];
    const float* Whr  = (const float*)d_in[10];
    const float* Cr   = (const float*)d_in[11];
    const float* br   = (const float*)d_in[12];
    const float* Wxh  = (const float*)d_in[13];
    const float* Whh  = (const float*)d_in[14];
    const float* bh   = (const float*)d_in[15];
    float* out = (float*)d_out;
    float* ws  = (float*)d_ws;
    unsigned* cnt = (unsigned*)(ws + WS_CNT);

    hipMemsetAsync(cnt, 0, 2 * sizeof(unsigned), stream);
    k_fused<<<STREAM0 + NSTREAM, 256, 0, stream>>>(
        X, E, H, dh, dt, Wxz, Whz, Cz, Wxr, Whr, Cr, Wxh, Whh,
        bz, br, bh, ws, cnt, out);
}

// Round 6
// 120.037 us; speedup vs baseline: 1.2337x; 1.2337x over previous
//
#include <hip/hip_runtime.h>
#include <math.h>

#define NN 8192
#define CC 256
#define LOG2N 13

typedef float f32x4 __attribute__((ext_vector_type(4)));

// ---------------- ws layout (floats) ----------------
// aggP : [128][256]   offset 0      (agg partial sums per 64-row chunk)
// zrP  : [7][4][256]  offset 32768  (matvec partials: m*4+q; m:0=Wxz 1=Whz 2=Cz 3=Wxr 4=Whr 5=Cr 6=Wxh)
#define WS_AGGP 0
#define WS_ZRP  32768

// A: agg partials + H->out copy (H read exactly once). 128 blocks x 256 threads;
// block b owns rows [b*64, b*64+64). Thread (g=t>>6, c=(t&63)*4) covers rows
// r=it*4+g (16 iters) and 16B of columns — copies H to out while accumulating.
__global__ void __launch_bounds__(256) k_agg(
        const float* __restrict__ E, const float* __restrict__ H,
        const int* __restrict__ dh, const int* __restrict__ dt,
        float* __restrict__ aggP, float* __restrict__ out) {
    __shared__ float e_sh[64];
    __shared__ f32x4 red[4][64];
    const int head = dh[0], tail = dt[0];
    const int t = threadIdx.x;
    const int i0 = blockIdx.x * 64;
    const size_t nn = (size_t)NN * NN;
    if (t < 64) {
        const int i = i0 + t;
        float e = 0.5f * E[(size_t)head * NN + i];
        if (head != tail) e += 0.5f * E[(size_t)tail * NN + i];
        if (i == tail) e += 0.5f;
        e_sh[t] = e;
    }
    __syncthreads();
    const int g = t >> 6, c = (t & 63) << 2;
    f32x4 acc = {0.f, 0.f, 0.f, 0.f};
    #pragma unroll
    for (int it = 0; it < 16; ++it) {
        const int r = it * 4 + g;
        const int row = i0 + r;
        const f32x4 hv = *(const f32x4*)(H + (size_t)row * CC + c);
        acc += hv * e_sh[r];
        if (row != head)
            *(f32x4*)(out + nn + (size_t)row * CC + c) = hv;
    }
    red[g][t & 63] = acc;
    __syncthreads();
    if (g == 0) {
        const f32x4 s = red[0][t] + red[1][t] + red[2][t] + red[3][t];
        *(f32x4*)(aggP + blockIdx.x * CC + (t << 2)) = s;
    }
}

// B: 7 matvec partial sets (all except Whh, which needs R). 28 blocks (m=0..6, q=0..3) x 256.
__global__ void __launch_bounds__(256) k_mv(
        const float* __restrict__ X, const float* __restrict__ H,
        const int* __restrict__ dh,
        const float* __restrict__ Wxz, const float* __restrict__ Whz,
        const float* __restrict__ Cz,  const float* __restrict__ Wxr,
        const float* __restrict__ Whr, const float* __restrict__ Cr,
        const float* __restrict__ Wxh,
        const float* __restrict__ aggP, float* __restrict__ zrP) {
    __shared__ float v_sh[64];
    const int m = blockIdx.x >> 2, q = blockIdx.x & 3;
    const int t = threadIdx.x;
    const float* W;
    switch (m) {
        case 0: W = Wxz; break; case 1: W = Whz; break; case 2: W = Cz; break;
        case 3: W = Wxr; break; case 4: W = Whr; break; case 5: W = Cr; break;
        default: W = Wxh; break;
    }
    if (t < 64) {
        const int k = q * 64 + t;
        float v;
        if (m == 1 || m == 4)      v = H[(size_t)dh[0] * CC + k];
        else if (m == 2 || m == 5) { v = 0.f; for (int b = 0; b < 128; ++b) v += aggP[b * CC + k]; }
        else                       v = X[k];
        v_sh[t] = v;
    }
    __syncthreads();
    float acc = 0.f;
    #pragma unroll
    for (int kk = 0; kk < 64; ++kk)
        acc += v_sh[kk] * W[(size_t)(q * 64 + kk) * CC + t];
    zrP[(m * 4 + q) * CC + t] = acc;
}

// C: pure-E streamer + GRU epilogue in block 0.
// Streamers: exact static partition — 2048 blocks x 256 threads x 32 f32x4 each
// = 16,777,216 f32x4 = all of E. Grid-stride sweep (whole grid covers 8.4 MB
// contiguous per step). 4 nt loads clustered before 4 stores (4x MLP).
__global__ void __launch_bounds__(256) k_big(
        const float* __restrict__ E, const float* __restrict__ H,
        const int* __restrict__ dh, const int* __restrict__ dt,
        const float* __restrict__ bz, const float* __restrict__ br,
        const float* __restrict__ bh, const float* __restrict__ Whh,
        const float* __restrict__ zrP, float* __restrict__ out) {
    const int head = dh[0], tail = dt[0];
    const size_t nn = (size_t)NN * NN;

    if (blockIdx.x == 0) {
        __shared__ float rs_sh[CC];
        const int c = threadIdx.x;
        float sz = bz[c], sr = br[c];
        #pragma unroll
        for (int p = 0; p < 12; ++p)  sz += zrP[p * CC + c];
        #pragma unroll
        for (int p = 12; p < 24; ++p) sr += zrP[p * CC + c];
        const float z = 1.f / (1.f + expf(-sz));
        const float r = 1.f / (1.f + expf(-sr));
        const float h = H[(size_t)head * CC + c];
        rs_sh[c] = h * r;
        __syncthreads();
        float acc = 0.f;
        #pragma unroll 16
        for (int k = 0; k < CC; ++k)
            acc += rs_sh[k] * Whh[(size_t)k * CC + c];
        float s = bh[c] + acc;
        #pragma unroll
        for (int p = 24; p < 28; ++p) s += zrP[p * CC + c];
        const float ht = tanhf(s);
        out[nn + (size_t)head * CC + c] = z * h + (1.f - z) * ht;
        return;
    }

    const size_t step = (size_t)2048 * 256;  // f32x4 units per sweep
    size_t idx = (size_t)(blockIdx.x - 1) * 256 + threadIdx.x;

    #pragma unroll
    for (int grp = 0; grp < 8; ++grp) {
        f32x4 v[4];
        #pragma unroll
        for (int j = 0; j < 4; ++j)
            v[j] = __builtin_nontemporal_load((const f32x4*)(E + ((idx + (size_t)j * step) << 2)));
        #pragma unroll
        for (int j = 0; j < 4; ++j) {
            const size_t e = (idx + (size_t)j * step) << 2;
            f32x4 o = v[j] * 0.5f;
            const int i = (int)(e >> LOG2N);
            if (i == head) {
                const int jj = (int)(e & (NN - 1));
                if (head != tail) {
                    const f32x4 w = *(const f32x4*)(E + (size_t)tail * NN + jj);
                    o += w * 0.5f;
                }
                if (tail >= jj && tail < jj + 4) o[tail - jj] += 0.5f;
            }
            *(f32x4*)(out + e) = o;
        }
        idx += 4 * step;
    }
}

extern "C" void kernel_launch(void* const* d_in, const int* in_sizes, int n_in,
                              void* d_out, int out_size, void* d_ws, size_t ws_size,
                              hipStream_t stream) {
    const float* X    = (const float*)d_in[0];
    const int*   dh   = (const int*)d_in[1];
    const int*   dt   = (const int*)d_in[2];
    const float* E    = (const float*)d_in[3];
    const float* H    = (const float*)d_in[4];
    const float* Wxz  = (const float*)d_in[5];
    const float* Whz  = (const float*)d_in[6];
    const float* Cz   = (const float*)d_in[7];
    const float* bz   = (const float*)d_in[8];
    const float* Wxr  = (const float*)d_in[9];
    const float* Whr  = (const float*)d_in[10];
    const float* Cr   = (const float*)d_in[11];
    const float* br   = (const float*)d_in[12];
    const float* Wxh  = (const float*)d_in[13];
    const float* Whh  = (const float*)d_in[14];
    const float* bh   = (const float*)d_in[15];
    float* out = (float*)d_out;
    float* ws  = (float*)d_ws;

    float* aggP = ws + WS_AGGP;
    float* zrP  = ws + WS_ZRP;

    k_agg<<<128, 256, 0, stream>>>(E, H, dh, dt, aggP, out);
    k_mv<<<28, 256, 0, stream>>>(X, H, dh, Wxz, Whz, Cz, Wxr, Whr, Cr, Wxh, aggP, zrP);
    k_big<<<2049, 256, 0, stream>>>(E, H, dh, dt, bz, br, bh, Whh, zrP, out);
}

// Round 7
// 112.721 us; speedup vs baseline: 1.3138x; 1.0649x over previous
//
#include <hip/hip_runtime.h>
#include <math.h>

#define NN 8192
#define CC 256
#define LOG2N 13

typedef float f32x4 __attribute__((ext_vector_type(4)));

// ---------------- ws layout (floats) ----------------
// sacc_z[256] | sacc_r[256] | xh_acc[256] | hh_acc[256]   (atomicAdd accumulators,
// zeroed each call by a captured hipMemsetAsync)
#define ACC_Z  0
#define ACC_R  256
#define ACC_XH 512
#define ACC_HH 768

#define NAGG    128                 // agg+conv chain blocks
#define NMV     20                  // 5 matvecs x 4 k-chunks
#define CHAIN   (NAGG + NMV)        // 148
#define NSTREAM 2048

// k1: one kernel, three block roles, NO cross-block sync (no fences, no spins).
//  - blocks [0,128): agg partials over 64 H-rows (copying H->out on the way, so H
//    is read exactly once), then push the partial through Cz and Cr (linearity:
//    sum of (partial @ C) over blocks == agg @ C) and atomicAdd into sacc_z/sacc_r.
//  - blocks [128,148): the 5 agg-independent matvecs (Wxz,Whz,Wxr,Whr,Wxh),
//    atomicAdd into sacc_z / sacc_r / xh_acc.
//  - blocks [148,2196): pure E streamers, R4-proven 2-deep nt-load pattern.
// Chain traffic per block <= 128 KB + L2-cached weights -> hides under ~88 us stream.
__global__ void __launch_bounds__(256) k1(
        const float* __restrict__ X, const float* __restrict__ E,
        const float* __restrict__ H,
        const int* __restrict__ dh, const int* __restrict__ dt,
        const float* __restrict__ Wxz, const float* __restrict__ Whz,
        const float* __restrict__ Cz,  const float* __restrict__ Wxr,
        const float* __restrict__ Whr, const float* __restrict__ Cr,
        const float* __restrict__ Wxh,
        float* __restrict__ acc_ws, float* __restrict__ out) {
    const int bid = blockIdx.x;
    const int t = threadIdx.x;
    const int head = dh[0], tail = dt[0];
    const size_t nn = (size_t)NN * NN;

    if (bid >= CHAIN) {
        // ---- pure E streamer: E_new = 0.5*E (+ head-row special case) ----
        const size_t total4 = nn >> 2;                 // 16,777,216 f32x4
        const size_t step = (size_t)NSTREAM * 256;     // 524,288
        size_t idx = (size_t)(bid - CHAIN) * 256 + t;
        for (; idx < total4; idx += 2 * step) {
            const size_t e0 = idx << 2;
            const size_t e1 = (idx + step) << 2;       // always in range (32 even sweeps)
            const f32x4 a = __builtin_nontemporal_load((const f32x4*)(E + e0));
            const f32x4 b = __builtin_nontemporal_load((const f32x4*)(E + e1));
            {
                f32x4 o = a * 0.5f;
                const int i = (int)(e0 >> LOG2N);
                if (i == head) {
                    const int j = (int)(e0 & (NN - 1));
                    if (head != tail) {
                        const f32x4 w = *(const f32x4*)(E + (size_t)tail * NN + j);
                        o += w * 0.5f;
                    }
                    if (tail >= j && tail < j + 4) o[tail - j] += 0.5f;
                }
                *(f32x4*)(out + e0) = o;
            }
            {
                f32x4 o = b * 0.5f;
                const int i = (int)(e1 >> LOG2N);
                if (i == head) {
                    const int j = (int)(e1 & (NN - 1));
                    if (head != tail) {
                        const f32x4 w = *(const f32x4*)(E + (size_t)tail * NN + j);
                        o += w * 0.5f;
                    }
                    if (tail >= j && tail < j + 4) o[tail - j] += 0.5f;
                }
                *(f32x4*)(out + e1) = o;
            }
        }
        return;
    }

    if (bid < NAGG) {
        // ---- agg chain: rows [bid*64, bid*64+64) ----
        __shared__ float e_sh[64];
        __shared__ f32x4 red[4][64];
        __shared__ float agg_sh[CC];
        const int i0 = bid * 64;
        if (t < 64) {
            const int i = i0 + t;
            float e = 0.5f * E[(size_t)head * NN + i];
            if (head != tail) e += 0.5f * E[(size_t)tail * NN + i];
            if (i == tail) e += 0.5f;
            e_sh[t] = e;
        }
        __syncthreads();
        const int g = t >> 6, c = (t & 63) << 2;
        f32x4 acc = {0.f, 0.f, 0.f, 0.f};
        #pragma unroll
        for (int it = 0; it < 16; ++it) {
            const int r = it * 4 + g;
            const int row = i0 + r;
            const f32x4 hv = *(const f32x4*)(H + (size_t)row * CC + c);
            acc += hv * e_sh[r];
            if (row != head)
                *(f32x4*)(out + nn + (size_t)row * CC + c) = hv;  // H copy, read-once
        }
        red[g][t & 63] = acc;
        __syncthreads();
        if (g == 0) {
            const f32x4 s = red[0][t] + red[1][t] + red[2][t] + red[3][t];
            *(f32x4*)(agg_sh + (t << 2)) = s;
        }
        __syncthreads();
        // push this block's agg partial through Cz / Cr (weights L2-cached per XCD)
        float pz = 0.f, pr = 0.f;
        #pragma unroll 8
        for (int k = 0; k < CC; ++k) {
            const float a = agg_sh[k];
            pz += a * Cz[(size_t)k * CC + t];
            pr += a * Cr[(size_t)k * CC + t];
        }
        atomicAdd(&acc_ws[ACC_Z + t], pz);
        atomicAdd(&acc_ws[ACC_R + t], pr);
        return;
    }

    // ---- mv chain: 5 matvecs x 4 chunks. m: 0=Wxz 1=Whz 2=Wxr 3=Whr 4=Wxh ----
    {
        const int mb = bid - NAGG;
        const int m = mb >> 2, q = mb & 3;
        __shared__ float v_sh[64];
        const float* W;
        float* dst;
        switch (m) {
            case 0: W = Wxz; dst = acc_ws + ACC_Z; break;
            case 1: W = Whz; dst = acc_ws + ACC_Z; break;
            case 2: W = Wxr; dst = acc_ws + ACC_R; break;
            case 3: W = Whr; dst = acc_ws + ACC_R; break;
            default: W = Wxh; dst = acc_ws + ACC_XH; break;
        }
        if (t < 64) {
            const int k = q * 64 + t;
            v_sh[t] = (m == 1 || m == 3) ? H[(size_t)head * CC + k] : X[k];
        }
        __syncthreads();
        float acc = 0.f;
        #pragma unroll
        for (int kk = 0; kk < 64; ++kk)
            acc += v_sh[kk] * W[(size_t)(q * 64 + kk) * CC + t];
        atomicAdd(&dst[t], acc);
    }
}

// k2: rs = h_head * sigmoid(br + sacc_r) (redundant per block — 1 KB read, trivial);
// each of 32 blocks does an 8-row slice of the Whh matvec, atomicAdd into hh_acc.
__global__ void __launch_bounds__(256) k2(
        const float* __restrict__ H, const int* __restrict__ dh,
        const float* __restrict__ br, const float* __restrict__ Whh,
        float* __restrict__ acc_ws) {
    __shared__ float rs_sh[CC];
    const int t = threadIdx.x;
    const int head = dh[0];
    const float sr = br[t] + acc_ws[ACC_R + t];
    const float r = 1.f / (1.f + expf(-sr));
    rs_sh[t] = H[(size_t)head * CC + t] * r;
    __syncthreads();
    const int k0 = blockIdx.x * 8;
    float acc = 0.f;
    #pragma unroll
    for (int j = 0; j < 8; ++j)
        acc += rs_sh[k0 + j] * Whh[(size_t)(k0 + j) * CC + t];
    atomicAdd(&acc_ws[ACC_HH + t], acc);
}

// k3: final head row of H_new.
__global__ void __launch_bounds__(256) k3(
        const float* __restrict__ H, const int* __restrict__ dh,
        const float* __restrict__ bz, const float* __restrict__ bh,
        const float* __restrict__ acc_ws, float* __restrict__ out) {
    const int t = threadIdx.x;
    const int head = dh[0];
    const float z = 1.f / (1.f + expf(-(bz[t] + acc_ws[ACC_Z + t])));
    const float ht = tanhf(bh[t] + acc_ws[ACC_XH + t] + acc_ws[ACC_HH + t]);
    const float h = H[(size_t)head * CC + t];
    out[(size_t)NN * NN + (size_t)head * CC + t] = z * h + (1.f - z) * ht;
}

extern "C" void kernel_launch(void* const* d_in, const int* in_sizes, int n_in,
                              void* d_out, int out_size, void* d_ws, size_t ws_size,
                              hipStream_t stream) {
    const float* X    = (const float*)d_in[0];
    const int*   dh   = (const int*)d_in[1];
    const int*   dt   = (const int*)d_in[2];
    const float* E    = (const float*)d_in[3];
    const float* H    = (const float*)d_in[4];
    const float* Wxz  = (const float*)d_in[5];
    const float* Whz  = (const float*)d_in[6];
    const float* Cz   = (const float*)d_in[7];
    const float* bz   = (const float*)d_in[8];
    const float* Wxr  = (const float*)d_in[9];
    const float* Whr  = (const float*)d_in[10];
    const float* Cr   = (const float*)d_in[11];
    const float* br   = (const float*)d_in[12];
    const float* Wxh  = (const float*)d_in[13];
    const float* Whh  = (const float*)d_in[14];
    const float* bh   = (const float*)d_in[15];
    float* out = (float*)d_out;
    float* acc_ws = (float*)d_ws;

    hipMemsetAsync(acc_ws, 0, 1024 * sizeof(float), stream);
    k1<<<CHAIN + NSTREAM, 256, 0, stream>>>(
        X, E, H, dh, dt, Wxz, Whz, Cz, Wxr, Whr, Cr, Wxh, acc_ws, out);
    k2<<<32, 256, 0, stream>>>(H, dh, br, Whh, acc_ws);
    k3<<<1, 256, 0, stream>>>(H, dh, bz, bh, acc_ws, out);
}